// Round 8
// baseline (574.866 us; speedup 1.0000x reference)
//
#include <hip/hip_runtime.h>
#include <stdint.h>

#define KQ     64    // queries per knn block (16 per wave)
#define NCHUNK 8
#define KNB    16
#define CAPGMX 768   // max candidate slots per query (12 u64 regs in merge)

typedef short short8 __attribute__((ext_vector_type(8)));
typedef float floatx4 __attribute__((ext_vector_type(4)));

__device__ __forceinline__ unsigned short f2bf(float x) {
  union { float f; uint32_t u; } v; v.f = x;
  uint32_t u = v.u + 0x7FFFu + ((v.u >> 16) & 1u);   // RNE
  return (unsigned short)(u >> 16);
}
__device__ __forceinline__ float bf2f(unsigned short b) {
  return __uint_as_float(((uint32_t)b) << 16);
}

// ---------------------------------------------------------------------------
// prep: pos4={x,y,z,pp}; panel[j] = 16 bf16 B-column k-slots (R3-verified):
//   b0={phx,phy,phz,phx,phy,phz,plx,ply} b1={plz,pph,ppl,1,1,0,0,0}
// sentinel rows (j>=N): b0=0, pph=bf16(1e30) -> t ~ 1e30, never selected.
// Wt = bf16 W_att^T; cnt_g zeroed.
// ---------------------------------------------------------------------------
__global__ void prep_kernel(const float* __restrict__ pos,
                            const float* __restrict__ W_att,
                            float4* __restrict__ pos4,
                            unsigned short* __restrict__ panel,
                            unsigned short* __restrict__ Wt,
                            int* __restrict__ cnt_g, int N, int Npad, int M) {
  int id = blockIdx.x * 256 + threadIdx.x;
  if (id < Npad) {
    int j = id;
    short8 b0 = {0, 0, 0, 0, 0, 0, 0, 0};
    short8 b1 = {0, 0, 0, (short)0x3F80, (short)0x3F80, 0, 0, 0};
    if (j < N) {
      float px = pos[3 * j], py = pos[3 * j + 1], pz = pos[3 * j + 2];
      float pp = fmaf(px, px, fmaf(py, py, pz * pz));
      pos4[j] = make_float4(px, py, pz, pp);
      unsigned short hx = f2bf(px), hy = f2bf(py), hz = f2bf(pz);
      unsigned short lx = f2bf(px - bf2f(hx)), ly = f2bf(py - bf2f(hy)),
                     lz = f2bf(pz - bf2f(hz));
      unsigned short hp = f2bf(pp), lp = f2bf(pp - bf2f(hp));
      b0[0] = hx; b0[1] = hy; b0[2] = hz; b0[3] = hx;
      b0[4] = hy; b0[5] = hz; b0[6] = lx; b0[7] = ly;
      b1[0] = lz; b1[1] = hp; b1[2] = lp;
    } else {
      b1[1] = (short)f2bf(1.0e30f);
    }
    *(short8*)(panel + (size_t)j * 16)     = b0;
    *(short8*)(panel + (size_t)j * 16 + 8) = b1;
  } else if (id < Npad + 128 * 128) {
    int t = id - Npad;
    int c = t >> 7, f = t & 127;
    Wt[f * 128 + c] = f2bf(W_att[t]);
  } else if (id < Npad + 128 * 128 + M) {
    cnt_g[id - Npad - 128 * 128] = 0;
  }
}

// ---------------------------------------------------------------------------
// knn: MFMA threshold-select. Wave = 16 queries (A-frag, R3-verified split:
// quad0={shx,shy,shz,slx,sly,slz,shx,shy} quad1={shz,1,1,qh,ql,0,0,0}).
// Each block = 64 queries x 1 chunk of Npad/8 points. Pass 1: c=mfma(A,B,0)
// ~ d2+O(eps); per-lane min over its col-class (16 disjoint groups) ->
// tau[q]=max of group mins >= t_(16). Pass 2: identical mfma, collect
// c<=tau+2eps hits straight to global cand_g (atomic slot). Exact-f32
// arbitration happens in fused merge -> same winner set as R2/R6.
// ---------------------------------------------------------------------------
__global__ __launch_bounds__(256) void knn_kernel(
    const float4* __restrict__ pos4, const unsigned short* __restrict__ panel,
    const int* __restrict__ idx, uint32_t* __restrict__ cand_g,
    int* __restrict__ cnt_g, int Npad, int M, int capg) {
  __shared__ float eps_s[64];

  const int tid = threadIdx.x;
  const int w = tid >> 6, lane = tid & 63;
  const int col = lane & 15, quad = lane >> 4;
  const int qg = blockIdx.x >> 3, chunk = blockIdx.x & 7;
  const int q0 = qg * KQ;
  const int chunkPts = Npad >> 3;       // multiple of 128
  const int nt = chunkPts >> 4;         // 16-point tiles
  const int jbase = chunk * chunkPts;

  // ---- A-frag build (R3-verified layout) ----
  short8 afr = {0, 0, 0, 0, 0, 0, 0, 0};
  {
    int ma = q0 + w * 16 + col; if (ma >= M) ma = M - 1;
    float4 qp = pos4[idx[ma]];
    float sx = -2.f * qp.x, sy = -2.f * qp.y, sz = -2.f * qp.z;
    unsigned short shx = f2bf(sx), shy = f2bf(sy), shz = f2bf(sz);
    unsigned short slx = f2bf(sx - bf2f(shx)), sly = f2bf(sy - bf2f(shy)),
                   slz = f2bf(sz - bf2f(shz));
    unsigned short qh = f2bf(qp.w), ql = f2bf(qp.w - bf2f(qh));
    if (quad == 0) {
      afr[0] = (short)shx; afr[1] = (short)shy; afr[2] = (short)shz;
      afr[3] = (short)slx; afr[4] = (short)sly; afr[5] = (short)slz;
      afr[6] = (short)shx; afr[7] = (short)shy;
    } else if (quad == 1) {
      afr[0] = (short)shz; afr[1] = (short)0x3F80; afr[2] = (short)0x3F80;
      afr[3] = (short)qh;  afr[4] = (short)ql;
    }
    if (quad == 0) {
      float qmax = fmaxf(fabsf(qp.x), fmaxf(fabsf(qp.y), fabsf(qp.z)));
      eps_s[w * 16 + col] = 1e-4f * (1.f + qmax) * (1.f + qmax) + 5e-5f;
    }
  }
  __syncthreads();

  const floatx4 zero4 = {0.f, 0.f, 0.f, 0.f};
  const short8* pan8 = (const short8*)panel;
  const int half = quad & 1;            // quads 2,3 read finite garbage; A=0 there

  // ---- pass 1: per-lane col-class t-mins ----
  floatx4 tmn = {3.4e38f, 3.4e38f, 3.4e38f, 3.4e38f};
  {
    short8 bcur = pan8[2 * (jbase + col) + half];
    for (int t = 0; t < nt; ++t) {
      short8 bnext = bcur;
      if (t + 1 < nt) bnext = pan8[2 * (jbase + (t + 1) * 16 + col) + half];
      floatx4 c = __builtin_amdgcn_mfma_f32_16x16x32_bf16(afr, bcur, zero4, 0, 0, 0);
#pragma unroll
      for (int r = 0; r < 4; ++r) tmn[r] = fminf(tmn[r], c[r]);
      bcur = bnext;
    }
  }

  // tau per query (C layout: row=query=quad*4+r, col=point-class)
  float taur[4]; int mqr[4];
#pragma unroll
  for (int r = 0; r < 4; ++r) {
    float v = tmn[r];
    v = fmaxf(v, __shfl_xor(v, 1));
    v = fmaxf(v, __shfl_xor(v, 2));
    v = fmaxf(v, __shfl_xor(v, 4));
    v = fmaxf(v, __shfl_xor(v, 8));
    int mq = q0 + w * 16 + quad * 4 + r;
    float eps = eps_s[w * 16 + quad * 4 + r];
    v = v + 2.f * eps + fabsf(v) * 1e-6f + 1e-7f;
    taur[r] = (mq < M) ? v : -3.4e38f;
    mqr[r] = (mq < M) ? mq : 0;
  }

  // ---- pass 2: identical mfma stream; collect hits to global ----
  {
    short8 bcur = pan8[2 * (jbase + col) + half];
    for (int t = 0; t < nt; ++t) {
      short8 bnext = bcur;
      if (t + 1 < nt) bnext = pan8[2 * (jbase + (t + 1) * 16 + col) + half];
      floatx4 c = __builtin_amdgcn_mfma_f32_16x16x32_bf16(afr, bcur, zero4, 0, 0, 0);
      const int j = jbase + t * 16 + col;
#pragma unroll
      for (int r = 0; r < 4; ++r) {
        if (c[r] <= taur[r]) {
          int sl = atomicAdd(&cnt_g[mqr[r]], 1);
          if (sl < capg) cand_g[(size_t)mqr[r] * capg + sl] = (uint32_t)j;
        }
      }
      bcur = bnext;
    }
  }
}

// ---------------------------------------------------------------------------
// fused: merge (exact-f32 d2 top-16 over <=capg cands) + LocSE + bf16-MFMA
// attention + softmax + mean + out GEMM + relu. 8 queries / 256 threads.
// ---------------------------------------------------------------------------
__global__ __launch_bounds__(256) void fused_kernel(
    const float* __restrict__ x, const float4* __restrict__ pos4,
    const int* __restrict__ idx, const float* __restrict__ W_pos,
    const float* __restrict__ b_pos, const unsigned short* __restrict__ Wt,
    const float* __restrict__ b_att, const float* __restrict__ W_glob,
    const float* __restrict__ b_glob, const uint32_t* __restrict__ cand_g,
    const int* __restrict__ cnt_g, float* __restrict__ out, int M, int capg) {
  __shared__ __align__(16) unsigned short fijb[8][16][136];
  __shared__ int nbr_s[128];
  __shared__ float4 qpos_s[8];
  __shared__ float agg[8][128];

  const int tid = threadIdx.x;
  const int wid = tid >> 6, lane = tid & 63;
  const int col = lane & 15, quad = lane >> 4;
  const int b = blockIdx.x;

  if (tid < 8) {
    int mq = b * 8 + tid; if (mq >= M) mq = M - 1;
    qpos_s[tid] = pos4[idx[mq]];
  }
  __syncthreads();

  // phase 0: exact-f32 d2 top-16 from cand_g (per wave: 2 queries)
#pragma unroll
  for (int i = 0; i < 2; ++i) {
    int q = wid * 2 + i;
    int mq = b * 8 + q; if (mq >= M) mq = M - 1;
    float4 qp = qpos_s[q];
    int nc = cnt_g[mq]; if (nc > capg) nc = capg;
    int nch = (nc + 63) >> 6;
    unsigned long long c[CAPGMX / 64];
#pragma unroll
    for (int ch = 0; ch < CAPGMX / 64; ++ch) c[ch] = ~0ull;
    for (int ch = 0; ch < nch; ++ch) {
      int s = ch * 64 + lane;
      if (s < nc) {
        uint32_t j = cand_g[(size_t)mq * capg + s];
        float4 pj = pos4[j];
        float dot = fmaf(qp.x, pj.x, fmaf(qp.y, pj.y, qp.z * pj.z));
        float tt  = fmaf(-2.f, dot, pj.w);
        float d2  = fmaxf(qp.w + tt, 0.f);
        c[ch] = ((unsigned long long)__float_as_uint(d2) << 32) | j;
      }
    }
#pragma unroll
    for (int r = 0; r < KNB; ++r) {
      unsigned long long mn = c[0];
#pragma unroll
      for (int ch = 1; ch < CAPGMX / 64; ++ch) mn = (c[ch] < mn) ? c[ch] : mn;
#pragma unroll
      for (int off = 1; off < 64; off <<= 1) {
        unsigned long long o = __shfl_xor(mn, off);
        mn = (o < mn) ? o : mn;
      }
      if (lane == 0) nbr_s[q * 16 + r] = (int)(uint32_t)mn;
#pragma unroll
      for (int ch = 0; ch < CAPGMX / 64; ++ch)
        if (c[ch] == mn) c[ch] = ~0ull;
    }
  }
  float wp[10];
#pragma unroll
  for (int t = 0; t < 10; ++t) wp[t] = W_pos[t * 64 + lane];
  float bp = b_pos[lane];
  __syncthreads();

  // phase 1a: x gather (f32 -> bf16), 2 threads per (q,k) row
  {
    int rr = tid >> 1, h = tid & 1;
    int jn = nbr_s[rr];
    const float4* src = (const float4*)(x + (size_t)jn * 64) + h * 8;
    short8* dst = (short8*)&fijb[rr >> 4][rr & 15][h * 32];
#pragma unroll
    for (int i = 0; i < 4; ++i) {
      float4 u = src[2 * i], v = src[2 * i + 1];
      short8 wv;
      wv[0] = (short)f2bf(u.x); wv[1] = (short)f2bf(u.y);
      wv[2] = (short)f2bf(u.z); wv[3] = (short)f2bf(u.w);
      wv[4] = (short)f2bf(v.x); wv[5] = (short)f2bf(v.y);
      wv[6] = (short)f2bf(v.z); wv[7] = (short)f2bf(v.w);
      dst[i] = wv;
    }
  }
  // phase 1b: LocSE rij (bf16); wave handles 2 queries, lane = channel
#pragma unroll
  for (int qi = 0; qi < 2; ++qi) {
    int q = wid * 2 + qi;
    float4 qp = qpos_s[q];
#pragma unroll 4
    for (int k = 0; k < 16; ++k) {
      int jn = nbr_s[q * 16 + k];
      float4 pj = pos4[jn];
      float vx = qp.x - pj.x, vy = qp.y - pj.y, vz = qp.z - pj.z;
      float dd = sqrtf(fmaf(vx, vx, fmaf(vy, vy, vz * vz)));
      float r = bp;
      r = fmaf(qp.x, wp[0], r); r = fmaf(qp.y, wp[1], r); r = fmaf(qp.z, wp[2], r);
      r = fmaf(pj.x, wp[3], r); r = fmaf(pj.y, wp[4], r); r = fmaf(pj.z, wp[5], r);
      r = fmaf(vx, wp[6], r);  r = fmaf(vy, wp[7], r);  r = fmaf(vz, wp[8], r);
      r = fmaf(dd, wp[9], r);
      r = fmaxf(r, 0.f);
      fijb[q][k][64 + lane] = f2bf(r);
    }
  }
  __syncthreads();

  // phase 2: MFMA attention + softmax + mean -> agg (LDS)
#pragma unroll 1
  for (int qi = 0; qi < 2; ++qi) {
    int q = wid * 2 + qi;

    short8 af[4];
#pragma unroll
    for (int cs = 0; cs < 4; ++cs)
      af[cs] = *(const short8*)&fijb[q][col][cs * 32 + quad * 8];

    floatx4 acc[8];
#pragma unroll
    for (int ft = 0; ft < 8; ++ft) {
      float bav = b_att[ft * 16 + col];
      floatx4 a = {bav, bav, bav, bav};
#pragma unroll
      for (int cs = 0; cs < 4; ++cs) {
        short8 bfrag =
            *(const short8*)&Wt[(ft * 16 + col) * 128 + cs * 32 + quad * 8];
        a = __builtin_amdgcn_mfma_f32_16x16x32_bf16(af[cs], bfrag, a, 0, 0, 0);
      }
      acc[ft] = a;
    }

    float rowmax[4], rowinv[4];
#pragma unroll
    for (int r = 0; r < 4; ++r) {
      float mx = acc[0][r];
#pragma unroll
      for (int ft = 1; ft < 8; ++ft) mx = fmaxf(mx, acc[ft][r]);
      mx = fmaxf(mx, __shfl_xor(mx, 1));
      mx = fmaxf(mx, __shfl_xor(mx, 2));
      mx = fmaxf(mx, __shfl_xor(mx, 4));
      mx = fmaxf(mx, __shfl_xor(mx, 8));
      float sm = 0.f;
#pragma unroll
      for (int ft = 0; ft < 8; ++ft) sm += __expf(acc[ft][r] - mx);
      sm += __shfl_xor(sm, 1);
      sm += __shfl_xor(sm, 2);
      sm += __shfl_xor(sm, 4);
      sm += __shfl_xor(sm, 8);
      rowmax[r] = mx;
      rowinv[r] = 1.0f / sm;
    }

#pragma unroll
    for (int ft = 0; ft < 8; ++ft) {
      float ap = 0.f;
#pragma unroll
      for (int r = 0; r < 4; ++r) {
        float s = __expf(acc[ft][r] - rowmax[r]) * rowinv[r];
        float fv = bf2f(fijb[q][quad * 4 + r][ft * 16 + col]);
        ap = fmaf(s, fv, ap);
      }
      ap += __shfl_xor(ap, 16);
      ap += __shfl_xor(ap, 32);
      if (quad == 0) agg[q][ft * 16 + col] = ap * (1.0f / 16.0f);
    }
  }
  __syncthreads();

  // phase 3: out = relu(agg @ W_glob + b_glob)
  {
    const int f = tid & 127, h = tid >> 7;
    float a0[4], a1[4];
#pragma unroll
    for (int i = 0; i < 4; ++i) {
      a0[i] = agg[h * 4 + i][lane];
      a1[i] = agg[h * 4 + i][64 + lane];
    }
    float bg = b_glob[f];
    float acc[4];
#pragma unroll
    for (int i = 0; i < 4; ++i) acc[i] = bg;
#pragma unroll 16
    for (int c = 0; c < 64; ++c) {
      float wv = W_glob[c * 128 + f];
#pragma unroll
      for (int i = 0; i < 4; ++i) acc[i] = fmaf(__shfl(a0[i], c), wv, acc[i]);
    }
#pragma unroll 16
    for (int c = 0; c < 64; ++c) {
      float wv = W_glob[(64 + c) * 128 + f];
#pragma unroll
      for (int i = 0; i < 4; ++i) acc[i] = fmaf(__shfl(a1[i], c), wv, acc[i]);
    }
#pragma unroll
    for (int i = 0; i < 4; ++i) {
      int m = b * 8 + h * 4 + i;
      if (m < M) out[m * 128 + f] = fmaxf(acc[i], 0.0f);
    }
  }
}

// ---------------------------------------------------------------------------
extern "C" void kernel_launch(void* const* d_in, const int* in_sizes, int n_in,
                              void* d_out, int out_size, void* d_ws,
                              size_t ws_size, hipStream_t stream) {
  const float* x      = (const float*)d_in[0];
  const float* pos    = (const float*)d_in[1];
  const int*   idx    = (const int*)d_in[2];
  const float* W_pos  = (const float*)d_in[3];
  const float* b_pos  = (const float*)d_in[4];
  const float* W_att  = (const float*)d_in[5];
  const float* b_att  = (const float*)d_in[6];
  const float* W_glob = (const float*)d_in[7];
  const float* b_glob = (const float*)d_in[8];
  float* out = (float*)d_out;

  const int N = in_sizes[1] / 3;
  const int M = in_sizes[2];
  const int Npad = (N + 1023) & ~1023;   // 8 chunks, each multiple of 128

  char* ws = (char*)d_ws;
  size_t o = 0;
  float4* pos4 = (float4*)(ws + o);               o += ((size_t)N * 16 + 255) & ~(size_t)255;
  unsigned short* panel = (unsigned short*)(ws + o); o += ((size_t)Npad * 32 + 255) & ~(size_t)255;
  unsigned short* Wt = (unsigned short*)(ws + o); o += (128 * 128 * 2 + 255) & ~(size_t)255;
  int* cnt_g = (int*)(ws + o);                    o += (((size_t)M * 4) + 255) & ~(size_t)255;
  // adaptive candidate capacity from remaining workspace
  size_t avail = (ws_size > o + 4096) ? (ws_size - o - 4096) : 0;
  int capg = (int)(avail / ((size_t)M * 4));
  if (capg > CAPGMX) capg = CAPGMX;
  if (capg < 64) capg = 64;              // degenerate ws; best effort
  uint32_t* cand_g = (uint32_t*)(ws + o);

  int prep_ids = Npad + 128 * 128 + M;
  prep_kernel<<<(prep_ids + 255) / 256, 256, 0, stream>>>(
      pos, W_att, pos4, panel, Wt, cnt_g, N, Npad, M);
  const int QG = (M + KQ - 1) / KQ;
  knn_kernel<<<QG * NCHUNK, 256, 0, stream>>>(pos4, panel, idx, cand_g, cnt_g,
                                              Npad, M, capg);
  fused_kernel<<<(M + 7) / 8, 256, 0, stream>>>(
      x, pos4, idx, W_pos, b_pos, Wt, b_att, W_glob, b_glob, cand_g, cnt_g,
      out, M, capg);
}

// Round 9
// 287.621 us; speedup vs baseline: 1.9987x; 1.9987x over previous
//
#include <hip/hip_runtime.h>
#include <stdint.h>

#define KQ     16    // queries per knn block (one A-frag row-set)
#define NCHUNK 4
#define KNB    16
#define CAPC   256   // LDS survivor cap per (query, chunk); E~54

typedef short short8 __attribute__((ext_vector_type(8)));
typedef float floatx4 __attribute__((ext_vector_type(4)));

__device__ __forceinline__ unsigned short f2bf(float x) {
  union { float f; uint32_t u; } v; v.f = x;
  uint32_t u = v.u + 0x7FFFu + ((v.u >> 16) & 1u);   // RNE
  return (unsigned short)(u >> 16);
}
__device__ __forceinline__ float bf2f(unsigned short b) {
  return __uint_as_float(((uint32_t)b) << 16);
}

// ---------------------------------------------------------------------------
// prep: pos4={x,y,z,pp}; panel[j] = 16 bf16 B k-slots (R3/R8-verified):
//   b0={phx,phy,phz,phx,phy,phz,plx,ply} b1={plz,pph,ppl,1,1,0,0,0}
// sentinels (j>=N): pph=1e30 -> t~1e30, never under tau. Wt = bf16 W_att^T.
// ---------------------------------------------------------------------------
__global__ void prep_kernel(const float* __restrict__ pos,
                            const float* __restrict__ W_att,
                            float4* __restrict__ pos4,
                            unsigned short* __restrict__ panel,
                            unsigned short* __restrict__ Wt, int N, int Npad) {
  int id = blockIdx.x * 256 + threadIdx.x;
  if (id < Npad) {
    int j = id;
    short8 b0 = {0, 0, 0, 0, 0, 0, 0, 0};
    short8 b1 = {0, 0, 0, (short)0x3F80, (short)0x3F80, 0, 0, 0};
    if (j < N) {
      float px = pos[3 * j], py = pos[3 * j + 1], pz = pos[3 * j + 2];
      float pp = fmaf(px, px, fmaf(py, py, pz * pz));
      pos4[j] = make_float4(px, py, pz, pp);
      unsigned short hx = f2bf(px), hy = f2bf(py), hz = f2bf(pz);
      unsigned short lx = f2bf(px - bf2f(hx)), ly = f2bf(py - bf2f(hy)),
                     lz = f2bf(pz - bf2f(hz));
      unsigned short hp = f2bf(pp), lp = f2bf(pp - bf2f(hp));
      b0[0] = hx; b0[1] = hy; b0[2] = hz; b0[3] = hx;
      b0[4] = hy; b0[5] = hz; b0[6] = lx; b0[7] = ly;
      b1[0] = lz; b1[1] = hp; b1[2] = lp;
    } else {
      b1[1] = (short)f2bf(1.0e30f);
    }
    *(short8*)(panel + (size_t)j * 16)     = b0;
    *(short8*)(panel + (size_t)j * 16 + 8) = b1;
  } else if (id < Npad + 128 * 128) {
    int t = id - Npad;
    int c = t >> 7, f = t & 127;
    Wt[f * 128 + c] = f2bf(W_att[t]);
  }
}

// ---------------------------------------------------------------------------
// knn: MFMA threshold-select, LDS collection (R6 topology). Block = 16
// queries x 1 chunk (Npad/4 pts); 4 waves each scan a quarter. Dual A-frags:
// A1 slots in k=0..15 (quads 0,1), A2 same content in k=16..31 (quads 2,3);
// one B-register set (quads 0,1 load tile t; quads 2,3 tile t+1) feeds both
// mfmas -> 32 points per load step, zero redundancy. tau: per-wave col-class
// mins combined in LDS (16 disjoint classes over chunk) -> max-of-mins +2eps
// (provable superset, R8-verified chain). Survivors -> LDS cand; pass 3
// extracts exact-f32 top-16 per chunk -> cand_out[m][chunk*16+r] (u64).
// ---------------------------------------------------------------------------
__global__ __launch_bounds__(256) void knn_kernel(
    const float4* __restrict__ pos4, const unsigned short* __restrict__ panel,
    const int* __restrict__ idx, unsigned long long* __restrict__ cand_out,
    int Npad, int N, int M) {
  __shared__ uint32_t cand[KQ][CAPC];
  __shared__ int cnt[KQ];
  __shared__ float gminw[4][KQ][16];   // [wave][query][class]
  __shared__ float tau_s[KQ];
  __shared__ float eps_s[KQ];
  __shared__ float4 qpos_s[KQ];

  const int tid = threadIdx.x;
  const int w = tid >> 6, lane = tid & 63;
  const int col = lane & 15, quad = lane >> 4;
  const int qg = blockIdx.x >> 2, chunk = blockIdx.x & 3;
  const int q0 = qg * KQ;
  const int chunkPts = Npad >> 2;            // multiple of 128
  const int wavePts = chunkPts >> 2;         // multiple of 32
  const int steps = wavePts >> 5;            // 32 points per step
  const int wbase = chunk * chunkPts + w * wavePts;

  // ---- A-frags (R8-verified content; A2 = same, shifted to k=16..31) ----
  short8 afrA = {0, 0, 0, 0, 0, 0, 0, 0};
  short8 afrB = {0, 0, 0, 0, 0, 0, 0, 0};
  {
    int ma = q0 + col; if (ma >= M) ma = M - 1;
    float4 qp = pos4[idx[ma]];
    float sx = -2.f * qp.x, sy = -2.f * qp.y, sz = -2.f * qp.z;
    unsigned short shx = f2bf(sx), shy = f2bf(sy), shz = f2bf(sz);
    unsigned short slx = f2bf(sx - bf2f(shx)), sly = f2bf(sy - bf2f(shy)),
                   slz = f2bf(sz - bf2f(shz));
    unsigned short qh = f2bf(qp.w), ql = f2bf(qp.w - bf2f(qh));
    if (quad == 0 || quad == 2) {
      short8 a;
      a[0] = (short)shx; a[1] = (short)shy; a[2] = (short)shz;
      a[3] = (short)slx; a[4] = (short)sly; a[5] = (short)slz;
      a[6] = (short)shx; a[7] = (short)shy;
      if (quad == 0) afrA = a; else afrB = a;
    } else {
      short8 a = {0, 0, 0, 0, 0, 0, 0, 0};
      a[0] = (short)shz; a[1] = (short)0x3F80; a[2] = (short)0x3F80;
      a[3] = (short)qh;  a[4] = (short)ql;
      if (quad == 1) afrA = a; else afrB = a;
    }
    if (w == 0 && quad == 0) {
      qpos_s[col] = qp;
      float qmax = fmaxf(fabsf(qp.x), fmaxf(fabsf(qp.y), fabsf(qp.z)));
      eps_s[col] = 1e-4f * (1.f + qmax) * (1.f + qmax) + 5e-5f;
    }
  }
  if (tid < KQ) cnt[tid] = 0;

  const floatx4 zero4 = {0.f, 0.f, 0.f, 0.f};
  const short8* pan8 = (const short8*)panel;
  // lane's B element: point = base + (quad>>1)*16 + col, half = quad&1
  const int lofs = ((quad >> 1) << 4) + col;
  const int half = quad & 1;

  // ---- pass 1: per-lane col-class t-mins over this wave's quarter ----
  floatx4 tm0 = {3.4e38f, 3.4e38f, 3.4e38f, 3.4e38f}, tm1 = tm0;
  {
    short8 bcur = pan8[2 * (wbase + lofs) + half];
    for (int s = 0; s < steps; ++s) {
      short8 bnext = bcur;
      if (s + 1 < steps) bnext = pan8[2 * (wbase + (s + 1) * 32 + lofs) + half];
      floatx4 c0 = __builtin_amdgcn_mfma_f32_16x16x32_bf16(afrA, bcur, zero4, 0, 0, 0);
      floatx4 c1 = __builtin_amdgcn_mfma_f32_16x16x32_bf16(afrB, bcur, zero4, 0, 0, 0);
#pragma unroll
      for (int r = 0; r < 4; ++r) {
        tm0[r] = fminf(tm0[r], c0[r]);
        tm1[r] = fminf(tm1[r], c1[r]);
      }
      bcur = bnext;
    }
  }
  // per-wave class-min (classes = point idx mod 16 = col); C row q = quad*4+r
#pragma unroll
  for (int r = 0; r < 4; ++r)
    gminw[w][quad * 4 + r][col] = fminf(tm0[r], tm1[r]);
  __syncthreads();
  // chunk tau[q] = max over 16 classes of min over 4 waves, + 2eps margin
  if (tid < KQ * 16) {
    int q = tid >> 4, c = tid & 15;
    float v = fminf(fminf(gminw[0][q][c], gminw[1][q][c]),
                    fminf(gminw[2][q][c], gminw[3][q][c]));
    gminw[0][q][c] = v;
  }
  __syncthreads();
  if (tid < KQ) {
    float t = gminw[0][tid][0];
#pragma unroll
    for (int c = 1; c < 16; ++c) t = fmaxf(t, gminw[0][tid][c]);
    tau_s[tid] = t + 2.f * eps_s[tid] + fabsf(t) * 1e-6f + 1e-7f;
  }
  __syncthreads();

  float taur0[4], taur1[4];
#pragma unroll
  for (int r = 0; r < 4; ++r) {
    taur0[r] = tau_s[quad * 4 + r];        // queries for c0 rows
    taur1[r] = tau_s[quad * 4 + r];        // same queries for c1 rows
  }

  // ---- pass 2: identical mfma stream; collect hits into LDS cand ----
  {
    short8 bcur = pan8[2 * (wbase + lofs) + half];
    for (int s = 0; s < steps; ++s) {
      short8 bnext = bcur;
      if (s + 1 < steps) bnext = pan8[2 * (wbase + (s + 1) * 32 + lofs) + half];
      floatx4 c0 = __builtin_amdgcn_mfma_f32_16x16x32_bf16(afrA, bcur, zero4, 0, 0, 0);
      floatx4 c1 = __builtin_amdgcn_mfma_f32_16x16x32_bf16(afrB, bcur, zero4, 0, 0, 0);
      const int jA = wbase + s * 32 + col;
      const int jB = jA + 16;
#pragma unroll
      for (int r = 0; r < 4; ++r) {
        if (c0[r] <= taur0[r]) {
          int qi = quad * 4 + r;
          int sl = atomicAdd(&cnt[qi], 1);
          if (sl < CAPC) cand[qi][sl] = (uint32_t)jA;
        }
        if (c1[r] <= taur1[r]) {
          int qi = quad * 4 + r;
          int sl = atomicAdd(&cnt[qi], 1);
          if (sl < CAPC) cand[qi][sl] = (uint32_t)jB;
        }
      }
      bcur = bnext;
    }
  }
  __syncthreads();

  // ---- pass 3: per wave 4 queries; exact-f32 top-16 of chunk -> global ----
#pragma unroll
  for (int i = 0; i < 4; ++i) {
    int qi = w * 4 + i;
    int m = q0 + qi;
    int nc = cnt[qi]; if (nc > CAPC) nc = CAPC;
    float4 qp = qpos_s[qi];
    unsigned long long c[CAPC / 64];
#pragma unroll
    for (int ch = 0; ch < CAPC / 64; ++ch) {
      c[ch] = ~0ull;
      int s = ch * 64 + lane;
      if (s < nc) {
        uint32_t j = cand[qi][s];
        float4 pj = pos4[j];
        float dot = fmaf(qp.x, pj.x, fmaf(qp.y, pj.y, qp.z * pj.z));
        float tt  = fmaf(-2.f, dot, pj.w);
        float d2  = fmaxf(qp.w + tt, 0.f);
        c[ch] = ((unsigned long long)__float_as_uint(d2) << 32) | j;
      }
    }
#pragma unroll
    for (int r = 0; r < KNB; ++r) {
      unsigned long long mn = c[0];
#pragma unroll
      for (int ch = 1; ch < CAPC / 64; ++ch) mn = (c[ch] < mn) ? c[ch] : mn;
#pragma unroll
      for (int off = 1; off < 64; off <<= 1) {
        unsigned long long o = __shfl_xor(mn, off);
        mn = (o < mn) ? o : mn;
      }
      if (m < M && lane == 0)
        cand_out[(size_t)m * 64 + chunk * 16 + r] = mn;
#pragma unroll
      for (int ch = 0; ch < CAPC / 64; ++ch)
        if (c[ch] == mn) c[ch] = ~0ull;
    }
  }
}

// ---------------------------------------------------------------------------
// fused (R7-verified): merge 64 chunk-cands -> 16 nbrs + LocSE + bf16-MFMA
// attention + softmax + mean + out GEMM + relu. 8 queries / 256 threads.
// ---------------------------------------------------------------------------
__global__ __launch_bounds__(256) void fused_kernel(
    const float* __restrict__ x, const float4* __restrict__ pos4,
    const int* __restrict__ idx, const float* __restrict__ W_pos,
    const float* __restrict__ b_pos, const unsigned short* __restrict__ Wt,
    const float* __restrict__ b_att, const float* __restrict__ W_glob,
    const float* __restrict__ b_glob,
    const unsigned long long* __restrict__ cand_out,
    float* __restrict__ out, int M) {
  __shared__ __align__(16) unsigned short fijb[8][16][136];
  __shared__ int nbr_s[128];
  __shared__ float4 qpos_s[8];
  __shared__ float agg[8][128];

  const int tid = threadIdx.x;
  const int wid = tid >> 6, lane = tid & 63;
  const int col = lane & 15, quad = lane >> 4;
  const int b = blockIdx.x;

  if (tid < 8) {
    int mq = b * 8 + tid; if (mq >= M) mq = M - 1;
    qpos_s[tid] = pos4[idx[mq]];
  }

  // phase 0: merge 4x16 chunk-top16 -> global top-16 (per wave: 2 queries)
#pragma unroll
  for (int i = 0; i < 2; ++i) {
    int q = wid * 2 + i;
    int mq = b * 8 + q; if (mq >= M) mq = M - 1;
    unsigned long long v = cand_out[(size_t)mq * 64 + lane];
#pragma unroll
    for (int r = 0; r < KNB; ++r) {
      unsigned long long mn = v;
#pragma unroll
      for (int off = 1; off < 64; off <<= 1) {
        unsigned long long o = __shfl_xor(mn, off);
        mn = (o < mn) ? o : mn;
      }
      if (lane == 0) nbr_s[q * 16 + r] = (int)(uint32_t)mn;
      if (v == mn) v = ~0ull;
    }
  }
  float wp[10];
#pragma unroll
  for (int t = 0; t < 10; ++t) wp[t] = W_pos[t * 64 + lane];
  float bp = b_pos[lane];
  __syncthreads();

  // phase 1a: x gather (f32 -> bf16), 2 threads per (q,k) row
  {
    int rr = tid >> 1, h = tid & 1;
    int jn = nbr_s[rr];
    const float4* src = (const float4*)(x + (size_t)jn * 64) + h * 8;
    short8* dst = (short8*)&fijb[rr >> 4][rr & 15][h * 32];
#pragma unroll
    for (int i = 0; i < 4; ++i) {
      float4 u = src[2 * i], v = src[2 * i + 1];
      short8 wv;
      wv[0] = (short)f2bf(u.x); wv[1] = (short)f2bf(u.y);
      wv[2] = (short)f2bf(u.z); wv[3] = (short)f2bf(u.w);
      wv[4] = (short)f2bf(v.x); wv[5] = (short)f2bf(v.y);
      wv[6] = (short)f2bf(v.z); wv[7] = (short)f2bf(v.w);
      dst[i] = wv;
    }
  }
  // phase 1b: LocSE rij (bf16); wave handles 2 queries, lane = channel
#pragma unroll
  for (int qi = 0; qi < 2; ++qi) {
    int q = wid * 2 + qi;
    float4 qp = qpos_s[q];
#pragma unroll 4
    for (int k = 0; k < 16; ++k) {
      int jn = nbr_s[q * 16 + k];
      float4 pj = pos4[jn];
      float vx = qp.x - pj.x, vy = qp.y - pj.y, vz = qp.z - pj.z;
      float dd = sqrtf(fmaf(vx, vx, fmaf(vy, vy, vz * vz)));
      float r = bp;
      r = fmaf(qp.x, wp[0], r); r = fmaf(qp.y, wp[1], r); r = fmaf(qp.z, wp[2], r);
      r = fmaf(pj.x, wp[3], r); r = fmaf(pj.y, wp[4], r); r = fmaf(pj.z, wp[5], r);
      r = fmaf(vx, wp[6], r);  r = fmaf(vy, wp[7], r);  r = fmaf(vz, wp[8], r);
      r = fmaf(dd, wp[9], r);
      r = fmaxf(r, 0.f);
      fijb[q][k][64 + lane] = f2bf(r);
    }
  }
  __syncthreads();

  // phase 2: MFMA attention + softmax + mean -> agg (LDS)
#pragma unroll 1
  for (int qi = 0; qi < 2; ++qi) {
    int q = wid * 2 + qi;

    short8 af[4];
#pragma unroll
    for (int cs = 0; cs < 4; ++cs)
      af[cs] = *(const short8*)&fijb[q][col][cs * 32 + quad * 8];

    floatx4 acc[8];
#pragma unroll
    for (int ft = 0; ft < 8; ++ft) {
      float bav = b_att[ft * 16 + col];
      floatx4 a = {bav, bav, bav, bav};
#pragma unroll
      for (int cs = 0; cs < 4; ++cs) {
        short8 bfrag =
            *(const short8*)&Wt[(ft * 16 + col) * 128 + cs * 32 + quad * 8];
        a = __builtin_amdgcn_mfma_f32_16x16x32_bf16(af[cs], bfrag, a, 0, 0, 0);
      }
      acc[ft] = a;
    }

    float rowmax[4], rowinv[4];
#pragma unroll
    for (int r = 0; r < 4; ++r) {
      float mx = acc[0][r];
#pragma unroll
      for (int ft = 1; ft < 8; ++ft) mx = fmaxf(mx, acc[ft][r]);
      mx = fmaxf(mx, __shfl_xor(mx, 1));
      mx = fmaxf(mx, __shfl_xor(mx, 2));
      mx = fmaxf(mx, __shfl_xor(mx, 4));
      mx = fmaxf(mx, __shfl_xor(mx, 8));
      float sm = 0.f;
#pragma unroll
      for (int ft = 0; ft < 8; ++ft) sm += __expf(acc[ft][r] - mx);
      sm += __shfl_xor(sm, 1);
      sm += __shfl_xor(sm, 2);
      sm += __shfl_xor(sm, 4);
      sm += __shfl_xor(sm, 8);
      rowmax[r] = mx;
      rowinv[r] = 1.0f / sm;
    }

#pragma unroll
    for (int ft = 0; ft < 8; ++ft) {
      float ap = 0.f;
#pragma unroll
      for (int r = 0; r < 4; ++r) {
        float s = __expf(acc[ft][r] - rowmax[r]) * rowinv[r];
        float fv = bf2f(fijb[q][quad * 4 + r][ft * 16 + col]);
        ap = fmaf(s, fv, ap);
      }
      ap += __shfl_xor(ap, 16);
      ap += __shfl_xor(ap, 32);
      if (quad == 0) agg[q][ft * 16 + col] = ap * (1.0f / 16.0f);
    }
  }
  __syncthreads();

  // phase 3: out = relu(agg @ W_glob + b_glob)
  {
    const int f = tid & 127, h = tid >> 7;
    float a0[4], a1[4];
#pragma unroll
    for (int i = 0; i < 4; ++i) {
      a0[i] = agg[h * 4 + i][lane];
      a1[i] = agg[h * 4 + i][64 + lane];
    }
    float bg = b_glob[f];
    float acc[4];
#pragma unroll
    for (int i = 0; i < 4; ++i) acc[i] = bg;
#pragma unroll 16
    for (int c = 0; c < 64; ++c) {
      float wv = W_glob[c * 128 + f];
#pragma unroll
      for (int i = 0; i < 4; ++i) acc[i] = fmaf(__shfl(a0[i], c), wv, acc[i]);
    }
#pragma unroll 16
    for (int c = 0; c < 64; ++c) {
      float wv = W_glob[(64 + c) * 128 + f];
#pragma unroll
      for (int i = 0; i < 4; ++i) acc[i] = fmaf(__shfl(a1[i], c), wv, acc[i]);
    }
#pragma unroll
    for (int i = 0; i < 4; ++i) {
      int m = b * 8 + h * 4 + i;
      if (m < M) out[m * 128 + f] = fmaxf(acc[i], 0.0f);
    }
  }
}

// ---------------------------------------------------------------------------
extern "C" void kernel_launch(void* const* d_in, const int* in_sizes, int n_in,
                              void* d_out, int out_size, void* d_ws,
                              size_t ws_size, hipStream_t stream) {
  const float* x      = (const float*)d_in[0];
  const float* pos    = (const float*)d_in[1];
  const int*   idx    = (const int*)d_in[2];
  const float* W_pos  = (const float*)d_in[3];
  const float* b_pos  = (const float*)d_in[4];
  const float* W_att  = (const float*)d_in[5];
  const float* b_att  = (const float*)d_in[6];
  const float* W_glob = (const float*)d_in[7];
  const float* b_glob = (const float*)d_in[8];
  float* out = (float*)d_out;

  const int N = in_sizes[1] / 3;
  const int M = in_sizes[2];
  const int Npad = (N + 511) & ~511;   // 4 chunks, each wave-quarter mult. 32

  char* ws = (char*)d_ws;
  size_t o = 0;
  float4* pos4 = (float4*)(ws + o);                  o += ((size_t)N * 16 + 255) & ~(size_t)255;
  unsigned short* panel = (unsigned short*)(ws + o); o += ((size_t)Npad * 32 + 255) & ~(size_t)255;
  unsigned short* Wt = (unsigned short*)(ws + o);    o += (128 * 128 * 2 + 255) & ~(size_t)255;
  unsigned long long* cand_out = (unsigned long long*)(ws + o);
  o += (((size_t)M * 64 * 8) + 255) & ~(size_t)255;

  int prep_ids = Npad + 128 * 128;
  prep_kernel<<<(prep_ids + 255) / 256, 256, 0, stream>>>(pos, W_att, pos4,
                                                          panel, Wt, N, Npad);
  const int QG = (M + KQ - 1) / KQ;
  knn_kernel<<<QG * NCHUNK, 256, 0, stream>>>(pos4, panel, idx, cand_out,
                                              Npad, N, M);
  fused_kernel<<<(M + 7) / 8, 256, 0, stream>>>(
      x, pos4, idx, W_pos, b_pos, Wt, b_att, W_glob, b_glob, cand_out, out, M);
}